// Round 1
// baseline (278.876 us; speedup 1.0000x reference)
//
#include <hip/hip_runtime.h>
#include <math.h>

namespace {

constexpr int B = 16, H = 512, W = 512;
constexpr int HWc = H * W;                 // 262144
constexpr size_t Nc = (size_t)B * HWc;     // 4194304

// Strip geometry: 64-lane wave holds cols [strip*42-11, strip*42+52].
// Boundary stencil (3x3) corrupts lanes 0,63; each of the 10 dilation steps
// corrupts one more lane per side -> valid central lanes 11..52 = 42 cols.
// 13 strips x 42 = 546 >= 512 (mask col < 512). Exact tiling, no overlap.
constexpr int NSTRIP = 13;
constexpr int CENT = 42;
constexpr int NBAND = 16;  // 512 / 32 rows

// ---------------- DPP lane shifts ----------------
// wave_shr:1 (0x138): lane i <- lane i-1 (lane 0 keeps own -> replicate edge)
// wave_shl:1 (0x130): lane i <- lane i+1 (lane 63 keeps own)
template <int CTRL>
__device__ __forceinline__ float dpp_shift1(float v) {
  int i = __float_as_int(v);
  int r = __builtin_amdgcn_update_dpp(i, i, CTRL, 0xF, 0xF, false);
  return __int_as_float(r);
}
__device__ __forceinline__ float hmax3(float v) {
  return fmaxf(fmaxf(dpp_shift1<0x138>(v), v), dpp_shift1<0x130>(v));
}
__device__ __forceinline__ float hmin3(float v) {
  return fminf(fminf(dpp_shift1<0x138>(v), v), dpp_shift1<0x130>(v));
}

__device__ __forceinline__ float wave_sum(float v) {
#pragma unroll
  for (int off = 32; off > 0; off >>= 1) v += __shfl_down(v, off);
  return v;
}

// --- block-wide sum over 256 threads (4 waves of 64). Valid on tid==0 only.
__device__ __forceinline__ float block_reduce_256(float v, float* sm, int tid) {
#pragma unroll
  for (int off = 32; off > 0; off >>= 1) v += __shfl_down(v, off);
  int lane = tid & 63, wid = tid >> 6;
  if (lane == 0) sm[wid] = v;
  __syncthreads();
  float r = 0.f;
  if (tid == 0) r = sm[0] + sm[1] + sm[2] + sm[3];
  __syncthreads();
  return r;
}

// CH==0: src map = sigmoid(logits), oth map = target.
// CH==1: src map = target,          oth map = sigmoid(logits).
// Row index clamped -> replicate border == -inf/+inf-padded pooling semantics.
template <int CH>
__device__ __forceinline__ float load_src(const float* __restrict__ Lg,
                                          const int* __restrict__ Tg, int gy,
                                          int colc) {
  gy = min(max(gy, 0), H - 1);
  if (CH == 0) {
    float x = Lg[gy * W + colc];
    return 1.f / (1.f + expf(-x));
  } else {
    return (float)Tg[gy * W + colc];
  }
}

// ---------------- fused: boundary-in-register + 10-step dilation ------------
// One wave per (strip, band, img, chain). Boundary maps are never
// materialized in global memory: the 3x3 dil-ero stencil is computed with the
// same DPP horizontal max/min + rolling vertical registers the dilation chain
// uses. BCE/dice partials are accumulated (once, in CH==0 blocks) over the
// exactly-tiling central region.
template <int CH>
__device__ __forceinline__ void fused_body(
    const float* __restrict__ Lg, const int* __restrict__ Tg, int lane,
    int strip, int band, int img, int bz, float* __restrict__ bce_p,
    float* __restrict__ sp_p, float* __restrict__ st_p,
    float* __restrict__ spt_p, float* __restrict__ chain_p) {
  int col = strip * CENT - 11 + lane;
  int colc = min(max(col, 0), W - 1);
  int y0 = band * 32;
  bool valid = (lane >= 11 && lane <= 52 && col < W);

  // ---- BCE / dice / tversky partials (only chain 0; central region only).
  // Loads hit L1: same rows/cols as the boundary passes below.
  if (CH == 0) {
    float s_bce = 0.f, s_p = 0.f, s_t = 0.f, s_pt = 0.f;
#pragma unroll
    for (int k = 0; k < 32; ++k) {
      float xl = Lg[(y0 + k) * W + colc];
      float t = (float)Tg[(y0 + k) * W + colc];
      float p = 1.f / (1.f + expf(-xl));
      s_bce += fmaxf(xl, 0.f) - xl * t + log1pf(expf(-fabsf(xl)));
      s_p += p;
      s_t += t;
      s_pt += p * t;
    }
    if (!valid) {
      s_bce = 0.f;
      s_p = 0.f;
      s_t = 0.f;
      s_pt = 0.f;
    }
    s_bce = wave_sum(s_bce);
    s_p = wave_sum(s_p);
    s_t = wave_sum(s_t);
    s_pt = wave_sum(s_pt);
    if (lane == 0) {
      int pi = (img * NBAND + band) * NSTRIP + strip;
      bce_p[pi] = s_bce;
      sp_p[pi] = s_p;
      st_p[pi] = s_t;
      spt_p[pi] = s_pt;
    }
  }

  // ---- other-map boundary, central rows y0..y0+31 (rolling 3-row stencil)
  float o[32];
  {
    float v0 = load_src<1 - CH>(Lg, Tg, y0 - 1, colc);
    float v1 = load_src<1 - CH>(Lg, Tg, y0, colc);
    float hx0 = hmax3(v0), hn0 = hmin3(v0);
    float hx1 = hmax3(v1), hn1 = hmin3(v1);
#pragma unroll
    for (int k = 0; k < 32; ++k) {
      float v2 = load_src<1 - CH>(Lg, Tg, y0 + 1 + k, colc);
      float hx2 = hmax3(v2), hn2 = hmin3(v2);
      o[k] = fmaxf(fmaxf(hx0, hx1), hx2) - fminf(fminf(hn0, hn1), hn2);
      hx0 = hx1;
      hx1 = hx2;
      hn0 = hn1;
      hn1 = hn2;
    }
  }

  // ---- src-map boundary incl. vertical halo: rows y0-10 .. y0+41
  float a[52];
  {
    float v0 = load_src<CH>(Lg, Tg, y0 - 11, colc);
    float v1 = load_src<CH>(Lg, Tg, y0 - 10, colc);
    float hx0 = hmax3(v0), hn0 = hmin3(v0);
    float hx1 = hmax3(v1), hn1 = hmin3(v1);
#pragma unroll
    for (int r = 0; r < 52; ++r) {
      float v2 = load_src<CH>(Lg, Tg, y0 - 9 + r, colc);
      float hx2 = hmax3(v2), hn2 = hmin3(v2);
      a[r] = fmaxf(fmaxf(hx0, hx1), hx2) - fminf(fminf(hn0, hn1), hn2);
      hx0 = hx1;
      hx1 = hx2;
      hn0 = hn1;
      hn1 = hn2;
    }
  }

  // ---- 10-step register-resident dilation + weighted L1 accumulation
  float acc = 0.f;
#pragma unroll
  for (int d = 1; d <= 10; ++d) {
    float hp = hmax3(a[d - 1]);
    float hc = hmax3(a[d]);
#pragma unroll
    for (int r = d; r <= 51 - d; ++r) {
      float hn = hmax3(a[r + 1]);
      float nv = fmaxf(fmaxf(hp, hc), hn);
      hp = hc;
      hc = hn;
      a[r] = nv;
    }
    const float wd = 0.1f * (float)d;
#pragma unroll
    for (int k = 0; k < 32; ++k) acc += wd * fabsf(a[10 + k] - o[k]);
  }
  acc = valid ? acc : 0.f;
  acc = wave_sum(acc);
  if (lane == 0) chain_p[(bz * NBAND + band) * NSTRIP + strip] = acc;
}

// 1 wave per block: no cross-wave cooperation anywhere, and 13 strips don't
// pack evenly into 4-wave blocks. __launch_bounds__(64,4): cap VGPRs at 128
// so a[52]+o[32]+rolling stencil regs stay resident (same budget the old
// chain_kernel compiled under).
__global__ void __launch_bounds__(64, 4) fused_kernel(
    const float* __restrict__ logits, const int* __restrict__ target,
    float* __restrict__ bce_p, float* __restrict__ sp_p,
    float* __restrict__ st_p, float* __restrict__ spt_p,
    float* __restrict__ chain_p) {
  int lane = threadIdx.x;
  int strip = blockIdx.x;   // 0..12
  int band = blockIdx.y;    // 0..15
  int bz = blockIdx.z;      // 0..31
  int img = bz & 15, chain = bz >> 4;
  const float* Lg = logits + (size_t)img * HWc;
  const int* Tg = target + (size_t)img * HWc;
  if (chain == 0)
    fused_body<0>(Lg, Tg, lane, strip, band, img, bz, bce_p, sp_p, st_p, spt_p,
                  chain_p);
  else
    fused_body<1>(Lg, Tg, lane, strip, band, img, bz, bce_p, sp_p, st_p, spt_p,
                  chain_p);
}

// ---------------- finalize ----------------
// Per-image sums parallelized 16 threads/image (13 iters each) instead of the
// old 1 thread/image x 128 serial dependent loads; per-image pow() spread
// across 16 threads instead of a serial loop on tid 0.
__global__ void finalize_kernel(const float* __restrict__ bce_p,
                                const float* __restrict__ sp_p,
                                const float* __restrict__ st_p,
                                const float* __restrict__ spt_p,
                                const float* __restrict__ chain_p,
                                float* __restrict__ out) {
  __shared__ float smr[4];
  __shared__ float smImg[16][3];
  __shared__ double smd[16][2];
  int tid = threadIdx.x;

  float s = 0.f;
  for (int i = tid; i < B * NBAND * NSTRIP; i += 256) s += bce_p[i];  // 3328
  float bce_sum = block_reduce_256(s, smr, tid);

  s = 0.f;
  for (int i = tid; i < 2 * B * NBAND * NSTRIP; i += 256) s += chain_p[i];
  float hd_sum = block_reduce_256(s, smr, tid);

  {
    int img = tid >> 4, part = tid & 15;  // 16 threads per image
    float sp = 0.f, st = 0.f, spt = 0.f;
    for (int j = part; j < NBAND * NSTRIP; j += 16) {  // 208 entries, 13 iters
      int idx = img * (NBAND * NSTRIP) + j;
      sp += sp_p[idx];
      st += st_p[idx];
      spt += spt_p[idx];
    }
#pragma unroll
    for (int off = 8; off > 0; off >>= 1) {
      sp += __shfl_down(sp, off, 16);
      st += __shfl_down(st, off, 16);
      spt += __shfl_down(spt, off, 16);
    }
    if (part == 0) {
      smImg[img][0] = sp;
      smImg[img][1] = st;
      smImg[img][2] = spt;
    }
  }
  __syncthreads();
  if (tid < 16) {
    double sp = smImg[tid][0], st = smImg[tid][1], spt = smImg[tid][2];
    double dice = (2.0 * spt + 1e-6) / (sp + st + 1e-6 + 1e-7);
    double tv = (spt + 1e-6) /
                (spt + 0.7 * (sp - spt) + 0.3 * (st - spt) + 1e-6 + 1e-7);
    smd[tid][0] = 1.0 - dice;
    smd[tid][1] = pow(1.0 - tv, 0.75);
  }
  __syncthreads();
  if (tid == 0) {
    double dice_l = 0.0, ft_l = 0.0;
    for (int i = 0; i < 16; ++i) {
      dice_l += smd[i][0];
      ft_l += smd[i][1];
    }
    dice_l /= 16.0;
    ft_l /= 16.0;
    const double Nd = (double)Nc;
    double bce = (double)bce_sum / Nd;
    double hd = ((double)hd_sum / Nd) / (5.5 + 1e-8);
    out[0] = (float)(bce + dice_l + ft_l + 0.1 * hd);
  }
}

}  // namespace

extern "C" void kernel_launch(void* const* d_in, const int* in_sizes, int n_in,
                              void* d_out, int out_size, void* d_ws,
                              size_t ws_size, hipStream_t stream) {
  const float* logits = (const float*)d_in[0];
  const int* target = (const int*)d_in[1];
  float* out = (float*)d_out;

  // Workspace: only small partial arrays now (boundary maps never hit global).
  // All slots below are fully written by fused_kernel each launch (harness
  // re-poisons ws between iterations -> no stale-read hazard).
  float* part = (float*)d_ws;
  float* bce_p = part;                 // 3328  = 16*16*13   (chain-0 waves)
  float* sp_p = part + 3328;           // 3328
  float* st_p = part + 2 * 3328;       // 3328
  float* spt_p = part + 3 * 3328;      // 3328
  float* chain_p = part + 4 * 3328;    // 6656  = 32*16*13

  fused_kernel<<<dim3(NSTRIP, NBAND, 2 * B), dim3(64), 0, stream>>>(
      logits, target, bce_p, sp_p, st_p, spt_p, chain_p);
  finalize_kernel<<<1, 256, 0, stream>>>(bce_p, sp_p, st_p, spt_p, chain_p,
                                         out);
}

// Round 2
// 185.334 us; speedup vs baseline: 1.5047x; 1.5047x over previous
//
#include <hip/hip_runtime.h>
#include <math.h>

namespace {

constexpr int B = 16, H = 512, W = 512;
constexpr int HWc = H * W;                 // 262144
constexpr size_t Nc = (size_t)B * HWc;     // 4194304

// Strip geometry: 64-lane wave holds cols [strip*42-11, strip*42+52].
// Boundary stencil (3x3) corrupts lanes 0,63; each of the 10 dilation steps
// corrupts one more lane per side -> valid central lanes 11..52 = 42 cols.
// 13 strips x 42 = 546 >= 512 (mask col < 512). Exact tiling, no overlap.
constexpr int NSTRIP = 13;
constexpr int CENT = 42;
constexpr int NBAND = 16;  // 512 / 32 rows
constexpr int NWORK = NSTRIP * NBAND * B * 2;  // 6656 wave work items

// ---------------- DPP lane shifts ----------------
// wave_shr:1 (0x138): lane i <- lane i-1 (lane 0 keeps own -> replicate edge)
// wave_shl:1 (0x130): lane i <- lane i+1 (lane 63 keeps own)
template <int CTRL>
__device__ __forceinline__ float dpp_shift1(float v) {
  int i = __float_as_int(v);
  int r = __builtin_amdgcn_update_dpp(i, i, CTRL, 0xF, 0xF, false);
  return __int_as_float(r);
}
__device__ __forceinline__ float hmax3(float v) {
  return fmaxf(fmaxf(dpp_shift1<0x138>(v), v), dpp_shift1<0x130>(v));
}
__device__ __forceinline__ float hmin3(float v) {
  return fminf(fminf(dpp_shift1<0x138>(v), v), dpp_shift1<0x130>(v));
}

__device__ __forceinline__ float wave_sum(float v) {
#pragma unroll
  for (int off = 32; off > 0; off >>= 1) v += __shfl_down(v, off);
  return v;
}

// --- block-wide sum over 256 threads (4 waves of 64). Valid on tid==0 only.
__device__ __forceinline__ float block_reduce_256(float v, float* sm, int tid) {
#pragma unroll
  for (int off = 32; off > 0; off >>= 1) v += __shfl_down(v, off);
  int lane = tid & 63, wid = tid >> 6;
  if (lane == 0) sm[wid] = v;
  __syncthreads();
  float r = 0.f;
  if (tid == 0) r = sm[0] + sm[1] + sm[2] + sm[3];
  __syncthreads();
  return r;
}

// CH==0: src map = sigmoid(logits), oth map = target.
// CH==1: src map = target,          oth map = sigmoid(logits).
// Row index clamped -> replicate border == -inf/+inf-padded pooling semantics.
template <int CH>
__device__ __forceinline__ float load_src(const float* __restrict__ Lg,
                                          const int* __restrict__ Tg, int gy,
                                          int colc) {
  gy = min(max(gy, 0), H - 1);
  if (CH == 0) {
    float x = Lg[gy * W + colc];
    return 1.f / (1.f + expf(-x));
  } else {
    return (float)Tg[gy * W + colc];
  }
}

// ---------------- fused: boundary-in-register + 10-step dilation ------------
// One wave per (strip, band, img, chain). Boundary maps are never
// materialized in global memory: the 3x3 dil-ero stencil is computed with the
// same DPP horizontal max/min + rolling vertical registers the dilation chain
// uses. BCE/dice partials are accumulated (once, in CH==0 waves) over the
// exactly-tiling central region.
template <int CH>
__device__ __forceinline__ void fused_body(
    const float* __restrict__ Lg, const int* __restrict__ Tg, int lane,
    int strip, int band, int img, int bz, float* __restrict__ bce_p,
    float* __restrict__ sp_p, float* __restrict__ st_p,
    float* __restrict__ spt_p, float* __restrict__ chain_p) {
  int col = strip * CENT - 11 + lane;
  int colc = min(max(col, 0), W - 1);
  int y0 = band * 32;
  bool valid = (lane >= 11 && lane <= 52 && col < W);

  // ---- BCE / dice / tversky partials (only chain 0; central region only).
  // Loads hit L1/L2: same rows/cols as the boundary passes below.
  if (CH == 0) {
    float s_bce = 0.f, s_p = 0.f, s_t = 0.f, s_pt = 0.f;
#pragma unroll
    for (int k = 0; k < 32; ++k) {
      float xl = Lg[(y0 + k) * W + colc];
      float t = (float)Tg[(y0 + k) * W + colc];
      float p = 1.f / (1.f + expf(-xl));
      s_bce += fmaxf(xl, 0.f) - xl * t + log1pf(expf(-fabsf(xl)));
      s_p += p;
      s_t += t;
      s_pt += p * t;
    }
    if (!valid) {
      s_bce = 0.f;
      s_p = 0.f;
      s_t = 0.f;
      s_pt = 0.f;
    }
    s_bce = wave_sum(s_bce);
    s_p = wave_sum(s_p);
    s_t = wave_sum(s_t);
    s_pt = wave_sum(s_pt);
    if (lane == 0) {
      int pi = (img * NBAND + band) * NSTRIP + strip;
      bce_p[pi] = s_bce;
      sp_p[pi] = s_p;
      st_p[pi] = s_t;
      spt_p[pi] = s_pt;
    }
  }

  // ---- other-map boundary, central rows y0..y0+31 (rolling 3-row stencil)
  float o[32];
  {
    float v0 = load_src<1 - CH>(Lg, Tg, y0 - 1, colc);
    float v1 = load_src<1 - CH>(Lg, Tg, y0, colc);
    float hx0 = hmax3(v0), hn0 = hmin3(v0);
    float hx1 = hmax3(v1), hn1 = hmin3(v1);
#pragma unroll
    for (int k = 0; k < 32; ++k) {
      float v2 = load_src<1 - CH>(Lg, Tg, y0 + 1 + k, colc);
      float hx2 = hmax3(v2), hn2 = hmin3(v2);
      o[k] = fmaxf(fmaxf(hx0, hx1), hx2) - fminf(fminf(hn0, hn1), hn2);
      hx0 = hx1;
      hx1 = hx2;
      hn0 = hn1;
      hn1 = hn2;
    }
  }

  // ---- src-map boundary incl. vertical halo: rows y0-10 .. y0+41
  float a[52];
  {
    float v0 = load_src<CH>(Lg, Tg, y0 - 11, colc);
    float v1 = load_src<CH>(Lg, Tg, y0 - 10, colc);
    float hx0 = hmax3(v0), hn0 = hmin3(v0);
    float hx1 = hmax3(v1), hn1 = hmin3(v1);
#pragma unroll
    for (int r = 0; r < 52; ++r) {
      float v2 = load_src<CH>(Lg, Tg, y0 - 9 + r, colc);
      float hx2 = hmax3(v2), hn2 = hmin3(v2);
      a[r] = fmaxf(fmaxf(hx0, hx1), hx2) - fminf(fminf(hn0, hn1), hn2);
      hx0 = hx1;
      hx1 = hx2;
      hn0 = hn1;
      hn1 = hn2;
    }
  }

  // ---- 10-step register-resident dilation + weighted L1 accumulation
  float acc = 0.f;
#pragma unroll
  for (int d = 1; d <= 10; ++d) {
    float hp = hmax3(a[d - 1]);
    float hc = hmax3(a[d]);
#pragma unroll
    for (int r = d; r <= 51 - d; ++r) {
      float hn = hmax3(a[r + 1]);
      float nv = fmaxf(fmaxf(hp, hc), hn);
      hp = hc;
      hc = hn;
      a[r] = nv;
    }
    const float wd = 0.1f * (float)d;
#pragma unroll
    for (int k = 0; k < 32; ++k) acc += wd * fabsf(a[10 + k] - o[k]);
  }
  acc = valid ? acc : 0.f;
  acc = wave_sum(acc);
  if (lane == 0) chain_p[(bz * NBAND + band) * NSTRIP + strip] = acc;
}

// 256-thread blocks, 4 independent waves each (proven launch shape of the
// 146 us chain_kernel). __launch_bounds__(256, 4) => 4 waves/EU => 128-VGPR
// budget so a[52]+o[32]+rolling stencil regs stay resident. R1 post-mortem:
// 64-thread blocks with (64,4) got only 64 VGPRs allocated -> remat/spill
// of the arrays -> 224 us latency-bound kernel at 7% HBM BW.
__global__ void __launch_bounds__(256, 4) fused_kernel(
    const float* __restrict__ logits, const int* __restrict__ target,
    float* __restrict__ bce_p, float* __restrict__ sp_p,
    float* __restrict__ st_p, float* __restrict__ spt_p,
    float* __restrict__ chain_p) {
  int tid = threadIdx.x;
  int lane = tid & 63;
  int wv = tid >> 6;
  int widx = blockIdx.x * 4 + wv;  // 0..6655, exact (NWORK/4 blocks)
  int strip = widx % NSTRIP;
  int rest = widx / NSTRIP;
  int band = rest & 15;
  int bz = rest >> 4;  // 0..31
  int img = bz & 15, chain = bz >> 4;
  const float* Lg = logits + (size_t)img * HWc;
  const int* Tg = target + (size_t)img * HWc;
  if (chain == 0)
    fused_body<0>(Lg, Tg, lane, strip, band, img, bz, bce_p, sp_p, st_p, spt_p,
                  chain_p);
  else
    fused_body<1>(Lg, Tg, lane, strip, band, img, bz, bce_p, sp_p, st_p, spt_p,
                  chain_p);
}

// ---------------- finalize ----------------
__global__ void finalize_kernel(const float* __restrict__ bce_p,
                                const float* __restrict__ sp_p,
                                const float* __restrict__ st_p,
                                const float* __restrict__ spt_p,
                                const float* __restrict__ chain_p,
                                float* __restrict__ out) {
  __shared__ float smr[4];
  __shared__ float smImg[16][3];
  __shared__ double smd[16][2];
  int tid = threadIdx.x;

  float s = 0.f;
  for (int i = tid; i < B * NBAND * NSTRIP; i += 256) s += bce_p[i];  // 3328
  float bce_sum = block_reduce_256(s, smr, tid);

  s = 0.f;
  for (int i = tid; i < 2 * B * NBAND * NSTRIP; i += 256) s += chain_p[i];
  float hd_sum = block_reduce_256(s, smr, tid);

  {
    int img = tid >> 4, part = tid & 15;  // 16 threads per image
    float sp = 0.f, st = 0.f, spt = 0.f;
    for (int j = part; j < NBAND * NSTRIP; j += 16) {  // 208 entries, 13 iters
      int idx = img * (NBAND * NSTRIP) + j;
      sp += sp_p[idx];
      st += st_p[idx];
      spt += spt_p[idx];
    }
#pragma unroll
    for (int off = 8; off > 0; off >>= 1) {
      sp += __shfl_down(sp, off, 16);
      st += __shfl_down(st, off, 16);
      spt += __shfl_down(spt, off, 16);
    }
    if (part == 0) {
      smImg[img][0] = sp;
      smImg[img][1] = st;
      smImg[img][2] = spt;
    }
  }
  __syncthreads();
  if (tid < 16) {
    double sp = smImg[tid][0], st = smImg[tid][1], spt = smImg[tid][2];
    double dice = (2.0 * spt + 1e-6) / (sp + st + 1e-6 + 1e-7);
    double tv = (spt + 1e-6) /
                (spt + 0.7 * (sp - spt) + 0.3 * (st - spt) + 1e-6 + 1e-7);
    smd[tid][0] = 1.0 - dice;
    smd[tid][1] = pow(1.0 - tv, 0.75);
  }
  __syncthreads();
  if (tid == 0) {
    double dice_l = 0.0, ft_l = 0.0;
    for (int i = 0; i < 16; ++i) {
      dice_l += smd[i][0];
      ft_l += smd[i][1];
    }
    dice_l /= 16.0;
    ft_l /= 16.0;
    const double Nd = (double)Nc;
    double bce = (double)bce_sum / Nd;
    double hd = ((double)hd_sum / Nd) / (5.5 + 1e-8);
    out[0] = (float)(bce + dice_l + ft_l + 0.1 * hd);
  }
}

}  // namespace

extern "C" void kernel_launch(void* const* d_in, const int* in_sizes, int n_in,
                              void* d_out, int out_size, void* d_ws,
                              size_t ws_size, hipStream_t stream) {
  const float* logits = (const float*)d_in[0];
  const int* target = (const int*)d_in[1];
  float* out = (float*)d_out;

  // Workspace: only small partial arrays (boundary maps never hit global).
  // All slots below are fully written by fused_kernel each launch.
  float* part = (float*)d_ws;
  float* bce_p = part;                 // 3328  = 16*16*13   (chain-0 waves)
  float* sp_p = part + 3328;           // 3328
  float* st_p = part + 2 * 3328;       // 3328
  float* spt_p = part + 3 * 3328;      // 3328
  float* chain_p = part + 4 * 3328;    // 6656  = 32*16*13

  fused_kernel<<<dim3(NWORK / 4, 1, 1), dim3(256), 0, stream>>>(
      logits, target, bce_p, sp_p, st_p, spt_p, chain_p);
  finalize_kernel<<<1, 256, 0, stream>>>(bce_p, sp_p, st_p, spt_p, chain_p,
                                         out);
}

// Round 3
// 167.742 us; speedup vs baseline: 1.6625x; 1.1049x over previous
//
#include <hip/hip_runtime.h>
#include <math.h>

namespace {

constexpr int B = 16, H = 512, W = 512;
constexpr int HWc = H * W;                 // 262144
constexpr size_t Nc = (size_t)B * HWc;     // 4194304

// Strip geometry: 64-lane wave holds cols [strip*42-11, strip*42+52].
// Boundary stencil (3x3) corrupts lanes 0,63; each of the 10 dilation steps
// corrupts one more lane per side -> valid central lanes 11..52 = 42 cols.
// 13 strips x 42 = 546 >= 512 (mask col < 512). Exact tiling, no overlap.
constexpr int NSTRIP = 13;
constexpr int CENT = 42;
constexpr int NBAND = 16;  // 512 / 32 rows
constexpr int NWORK = NSTRIP * NBAND * B * 2;  // 6656 wave work items

// ---------------- DPP lane shifts ----------------
// wave_shr:1 (0x138): lane i <- lane i-1 (lane 0 keeps own -> replicate edge)
// wave_shl:1 (0x130): lane i <- lane i+1 (lane 63 keeps own)
template <int CTRL>
__device__ __forceinline__ float dpp_shift1(float v) {
  int i = __float_as_int(v);
  int r = __builtin_amdgcn_update_dpp(i, i, CTRL, 0xF, 0xF, false);
  return __int_as_float(r);
}
__device__ __forceinline__ float hmax3(float v) {
  return fmaxf(fmaxf(dpp_shift1<0x138>(v), v), dpp_shift1<0x130>(v));
}
__device__ __forceinline__ float hmin3(float v) {
  return fminf(fminf(dpp_shift1<0x138>(v), v), dpp_shift1<0x130>(v));
}

__device__ __forceinline__ float wave_sum(float v) {
#pragma unroll
  for (int off = 32; off > 0; off >>= 1) v += __shfl_down(v, off);
  return v;
}

// --- block-wide sum over 256 threads (4 waves of 64). Valid on tid==0 only.
__device__ __forceinline__ float block_reduce_256(float v, float* sm, int tid) {
#pragma unroll
  for (int off = 32; off > 0; off >>= 1) v += __shfl_down(v, off);
  int lane = tid & 63, wid = tid >> 6;
  if (lane == 0) sm[wid] = v;
  __syncthreads();
  float r = 0.f;
  if (tid == 0) r = sm[0] + sm[1] + sm[2] + sm[3];
  __syncthreads();
  return r;
}

// CH==0: src map = sigmoid(logits), oth map = target.
// CH==1: src map = target,          oth map = sigmoid(logits).
// Row index clamped -> replicate border == -inf/+inf-padded pooling semantics.
template <int CH>
__device__ __forceinline__ float load_src(const float* __restrict__ Lg,
                                          const int* __restrict__ Tg, int gy,
                                          int colc) {
  gy = min(max(gy, 0), H - 1);
  if (CH == 0) {
    float x = Lg[gy * W + colc];
    return 1.f / (1.f + expf(-x));
  } else {
    return (float)Tg[gy * W + colc];
  }
}

// ---- dilation steps via template recursion.
// R2 post-mortem: a runtime d-loop around `for (r=d; r<=51-d; ++r)` defeats
// nested full-unroll -> runtime-indexed a[] -> arrays demoted to scratch
// (VGPR_Count 64, 120 MB of scratch WRITE_SIZE, 112 us memory-bound kernel).
// With D a template parameter every index is compile-time, SROA promotes
// a[]/o[] to VGPRs structurally, independent of unroll heuristics.
template <int D>
__device__ __forceinline__ void dilate_steps(float (&a)[52],
                                             const float (&o)[32],
                                             float& acc) {
  if constexpr (D <= 10) {
    float hp = hmax3(a[D - 1]);
    float hc = hmax3(a[D]);
#pragma unroll
    for (int r = D; r <= 51 - D; ++r) {  // trip count 52-2D: compile-time
      float hn = hmax3(a[r + 1]);
      float nv = fmaxf(fmaxf(hp, hc), hn);
      hp = hc;
      hc = hn;
      a[r] = nv;
    }
    constexpr float wd = 0.1f * (float)D;
#pragma unroll
    for (int k = 0; k < 32; ++k) acc += wd * fabsf(a[10 + k] - o[k]);
    dilate_steps<D + 1>(a, o, acc);
  }
}

// ---------------- fused: boundary-in-register + 10-step dilation ------------
// One wave per (strip, band, img, chain). Boundary maps are never
// materialized in global memory: the 3x3 dil-ero stencil is computed with the
// same DPP horizontal max/min + rolling vertical registers the dilation chain
// uses. BCE/dice partials are accumulated (once, in CH==0 waves) over the
// exactly-tiling central region.
template <int CH>
__device__ __forceinline__ void fused_body(
    const float* __restrict__ Lg, const int* __restrict__ Tg, int lane,
    int strip, int band, int img, int bz, float* __restrict__ bce_p,
    float* __restrict__ sp_p, float* __restrict__ st_p,
    float* __restrict__ spt_p, float* __restrict__ chain_p) {
  int col = strip * CENT - 11 + lane;
  int colc = min(max(col, 0), W - 1);
  int y0 = band * 32;
  bool valid = (lane >= 11 && lane <= 52 && col < W);

  // ---- BCE / dice / tversky partials (only chain 0; central region only).
  // Loads hit L1/L2: same rows/cols as the boundary passes below.
  if (CH == 0) {
    float s_bce = 0.f, s_p = 0.f, s_t = 0.f, s_pt = 0.f;
#pragma unroll
    for (int k = 0; k < 32; ++k) {
      float xl = Lg[(y0 + k) * W + colc];
      float t = (float)Tg[(y0 + k) * W + colc];
      float p = 1.f / (1.f + expf(-xl));
      s_bce += fmaxf(xl, 0.f) - xl * t + log1pf(expf(-fabsf(xl)));
      s_p += p;
      s_t += t;
      s_pt += p * t;
    }
    if (!valid) {
      s_bce = 0.f;
      s_p = 0.f;
      s_t = 0.f;
      s_pt = 0.f;
    }
    s_bce = wave_sum(s_bce);
    s_p = wave_sum(s_p);
    s_t = wave_sum(s_t);
    s_pt = wave_sum(s_pt);
    if (lane == 0) {
      int pi = (img * NBAND + band) * NSTRIP + strip;
      bce_p[pi] = s_bce;
      sp_p[pi] = s_p;
      st_p[pi] = s_t;
      spt_p[pi] = s_pt;
    }
  }

  // ---- other-map boundary, central rows y0..y0+31 (rolling 3-row stencil)
  float o[32];
  {
    float v0 = load_src<1 - CH>(Lg, Tg, y0 - 1, colc);
    float v1 = load_src<1 - CH>(Lg, Tg, y0, colc);
    float hx0 = hmax3(v0), hn0 = hmin3(v0);
    float hx1 = hmax3(v1), hn1 = hmin3(v1);
#pragma unroll
    for (int k = 0; k < 32; ++k) {
      float v2 = load_src<1 - CH>(Lg, Tg, y0 + 1 + k, colc);
      float hx2 = hmax3(v2), hn2 = hmin3(v2);
      o[k] = fmaxf(fmaxf(hx0, hx1), hx2) - fminf(fminf(hn0, hn1), hn2);
      hx0 = hx1;
      hx1 = hx2;
      hn0 = hn1;
      hn1 = hn2;
    }
  }

  // ---- src-map boundary incl. vertical halo: rows y0-10 .. y0+41
  float a[52];
  {
    float v0 = load_src<CH>(Lg, Tg, y0 - 11, colc);
    float v1 = load_src<CH>(Lg, Tg, y0 - 10, colc);
    float hx0 = hmax3(v0), hn0 = hmin3(v0);
    float hx1 = hmax3(v1), hn1 = hmin3(v1);
#pragma unroll
    for (int r = 0; r < 52; ++r) {
      float v2 = load_src<CH>(Lg, Tg, y0 - 9 + r, colc);
      float hx2 = hmax3(v2), hn2 = hmin3(v2);
      a[r] = fmaxf(fmaxf(hx0, hx1), hx2) - fminf(fminf(hn0, hn1), hn2);
      hx0 = hx1;
      hx1 = hx2;
      hn0 = hn1;
      hn1 = hn2;
    }
  }

  // ---- 10-step register-resident dilation + weighted L1 accumulation
  float acc = 0.f;
  dilate_steps<1>(a, o, acc);

  acc = valid ? acc : 0.f;
  acc = wave_sum(acc);
  if (lane == 0) chain_p[(bz * NBAND + band) * NSTRIP + strip] = acc;
}

// 256-thread blocks, 4 independent waves each. __launch_bounds__(256, 4) =>
// 4 blocks/CU => 4 waves/SIMD => 128-VGPR budget: enough for the ~95-110
// live VGPRs of a[52]+o[32]+rolling temps once SROA promotes them.
__global__ void __launch_bounds__(256, 4) fused_kernel(
    const float* __restrict__ logits, const int* __restrict__ target,
    float* __restrict__ bce_p, float* __restrict__ sp_p,
    float* __restrict__ st_p, float* __restrict__ spt_p,
    float* __restrict__ chain_p) {
  int tid = threadIdx.x;
  int lane = tid & 63;
  int wv = tid >> 6;
  int widx = blockIdx.x * 4 + wv;  // 0..6655, exact (NWORK/4 blocks)
  int strip = widx % NSTRIP;
  int rest = widx / NSTRIP;
  int band = rest & 15;
  int bz = rest >> 4;  // 0..31
  int img = bz & 15, chain = bz >> 4;
  const float* Lg = logits + (size_t)img * HWc;
  const int* Tg = target + (size_t)img * HWc;
  if (chain == 0)
    fused_body<0>(Lg, Tg, lane, strip, band, img, bz, bce_p, sp_p, st_p, spt_p,
                  chain_p);
  else
    fused_body<1>(Lg, Tg, lane, strip, band, img, bz, bce_p, sp_p, st_p, spt_p,
                  chain_p);
}

// ---------------- finalize ----------------
__global__ void finalize_kernel(const float* __restrict__ bce_p,
                                const float* __restrict__ sp_p,
                                const float* __restrict__ st_p,
                                const float* __restrict__ spt_p,
                                const float* __restrict__ chain_p,
                                float* __restrict__ out) {
  __shared__ float smr[4];
  __shared__ float smImg[16][3];
  __shared__ double smd[16][2];
  int tid = threadIdx.x;

  float s = 0.f;
  for (int i = tid; i < B * NBAND * NSTRIP; i += 256) s += bce_p[i];  // 3328
  float bce_sum = block_reduce_256(s, smr, tid);

  s = 0.f;
  for (int i = tid; i < 2 * B * NBAND * NSTRIP; i += 256) s += chain_p[i];
  float hd_sum = block_reduce_256(s, smr, tid);

  {
    int img = tid >> 4, part = tid & 15;  // 16 threads per image
    float sp = 0.f, st = 0.f, spt = 0.f;
    for (int j = part; j < NBAND * NSTRIP; j += 16) {  // 208 entries, 13 iters
      int idx = img * (NBAND * NSTRIP) + j;
      sp += sp_p[idx];
      st += st_p[idx];
      spt += spt_p[idx];
    }
#pragma unroll
    for (int off = 8; off > 0; off >>= 1) {
      sp += __shfl_down(sp, off, 16);
      st += __shfl_down(st, off, 16);
      spt += __shfl_down(spt, off, 16);
    }
    if (part == 0) {
      smImg[img][0] = sp;
      smImg[img][1] = st;
      smImg[img][2] = spt;
    }
  }
  __syncthreads();
  if (tid < 16) {
    double sp = smImg[tid][0], st = smImg[tid][1], spt = smImg[tid][2];
    double dice = (2.0 * spt + 1e-6) / (sp + st + 1e-6 + 1e-7);
    double tv = (spt + 1e-6) /
                (spt + 0.7 * (sp - spt) + 0.3 * (st - spt) + 1e-6 + 1e-7);
    smd[tid][0] = 1.0 - dice;
    smd[tid][1] = pow(1.0 - tv, 0.75);
  }
  __syncthreads();
  if (tid == 0) {
    double dice_l = 0.0, ft_l = 0.0;
    for (int i = 0; i < 16; ++i) {
      dice_l += smd[i][0];
      ft_l += smd[i][1];
    }
    dice_l /= 16.0;
    ft_l /= 16.0;
    const double Nd = (double)Nc;
    double bce = (double)bce_sum / Nd;
    double hd = ((double)hd_sum / Nd) / (5.5 + 1e-8);
    out[0] = (float)(bce + dice_l + ft_l + 0.1 * hd);
  }
}

}  // namespace

extern "C" void kernel_launch(void* const* d_in, const int* in_sizes, int n_in,
                              void* d_out, int out_size, void* d_ws,
                              size_t ws_size, hipStream_t stream) {
  const float* logits = (const float*)d_in[0];
  const int* target = (const int*)d_in[1];
  float* out = (float*)d_out;

  // Workspace: only small partial arrays (boundary maps never hit global).
  // All slots below are fully written by fused_kernel each launch.
  float* part = (float*)d_ws;
  float* bce_p = part;                 // 3328  = 16*16*13   (chain-0 waves)
  float* sp_p = part + 3328;           // 3328
  float* st_p = part + 2 * 3328;       // 3328
  float* spt_p = part + 3 * 3328;      // 3328
  float* chain_p = part + 4 * 3328;    // 6656  = 32*16*13

  fused_kernel<<<dim3(NWORK / 4, 1, 1), dim3(256), 0, stream>>>(
      logits, target, bce_p, sp_p, st_p, spt_p, chain_p);
  finalize_kernel<<<1, 256, 0, stream>>>(bce_p, sp_p, st_p, spt_p, chain_p,
                                         out);
}

// Round 4
// 140.436 us; speedup vs baseline: 1.9858x; 1.1944x over previous
//
#include <hip/hip_runtime.h>
#include <math.h>

namespace {

constexpr int B = 16, H = 512, W = 512;
constexpr int HWc = H * W;                 // 262144
constexpr size_t Nc = (size_t)B * HWc;     // 4194304

// Strip geometry: 64-lane wave holds cols [strip*42-11, strip*42+52].
// Boundary stencil (3x3) corrupts lanes 0,63; each of the 10 dilation steps
// corrupts one more lane per side -> valid central lanes 11..52 = 42 cols.
// 13 strips x 42 = 546 >= 512 (mask col < 512). Exact tiling, no overlap.
constexpr int NSTRIP = 13;
constexpr int CENT = 42;
constexpr int NBAND = 16;  // 512 / 32 rows
constexpr int NWORK = NSTRIP * NBAND * B * 2;  // 6656 wave work items
constexpr int NBCE = B * 64;                   // 1024 bce/dice partial blocks

// ---------------- DPP lane shifts ----------------
// wave_shr:1 (0x138): lane i <- lane i-1 (lane 0 keeps own -> replicate edge)
// wave_shl:1 (0x130): lane i <- lane i+1 (lane 63 keeps own)
template <int CTRL>
__device__ __forceinline__ float dpp_shift1(float v) {
  int i = __float_as_int(v);
  int r = __builtin_amdgcn_update_dpp(i, i, CTRL, 0xF, 0xF, false);
  return __int_as_float(r);
}
__device__ __forceinline__ float hmax3(float v) {
  return fmaxf(fmaxf(dpp_shift1<0x138>(v), v), dpp_shift1<0x130>(v));
}
__device__ __forceinline__ float hmin3(float v) {
  return fminf(fminf(dpp_shift1<0x138>(v), v), dpp_shift1<0x130>(v));
}

__device__ __forceinline__ float wave_sum(float v) {
#pragma unroll
  for (int off = 32; off > 0; off >>= 1) v += __shfl_down(v, off);
  return v;
}

// --- block-wide sum over 256 threads (4 waves of 64). Valid on tid==0 only.
__device__ __forceinline__ float block_reduce_256(float v, float* sm, int tid) {
#pragma unroll
  for (int off = 32; off > 0; off >>= 1) v += __shfl_down(v, off);
  int lane = tid & 63, wid = tid >> 6;
  if (lane == 0) sm[wid] = v;
  __syncthreads();
  float r = 0.f;
  if (tid == 0) r = sm[0] + sm[1] + sm[2] + sm[3];
  __syncthreads();
  return r;
}

// ---------------- streaming BCE + dice/tversky partial kernel --------------
// R3 post-mortem: the fused stencil kernel is VALU-bound (85.9% busy); the
// BCE pass inside it (64 extra loads + 32 libm log1pf ~20 instr each + 32
// slow sigmoids per CH0 wave) is pure streaming work that doesn't belong in
// the register-starved kernel. As its own float4 kernel it is memory-bound
// (~33.5 MB -> ~6 us).
// Identity used: max(x,0) - x*t + log1p(exp(-|x|)) == x*(1-t) + log(1+e^-x).
__global__ void __launch_bounds__(256) bce_kernel(
    const float* __restrict__ logits, const int* __restrict__ target,
    float* __restrict__ bceA, float* __restrict__ spA, float* __restrict__ stA,
    float* __restrict__ sptA) {
  __shared__ float smr[4];
  int img = blockIdx.x >> 6, seg = blockIdx.x & 63;  // 64 blocks/image
  const float4* L4 =
      (const float4*)(logits + (size_t)img * HWc + (size_t)seg * 4096);
  const int4* T4 =
      (const int4*)(target + (size_t)img * HWc + (size_t)seg * 4096);
  int tid = threadIdx.x;
  float s_bce = 0.f, s_p = 0.f, s_t = 0.f, s_pt = 0.f;
#pragma unroll
  for (int it = 0; it < 4; ++it) {
    float4 x4 = L4[it * 256 + tid];
    int4 t4 = T4[it * 256 + tid];
    float xs[4] = {x4.x, x4.y, x4.z, x4.w};
    int ts[4] = {t4.x, t4.y, t4.z, t4.w};
#pragma unroll
    for (int j = 0; j < 4; ++j) {
      float x = xs[j];
      float tf = (float)ts[j];
      float e = __expf(-x);                       // v_mul + v_exp
      float p = __builtin_amdgcn_rcpf(1.f + e);   // sigmoid
      s_p += p;
      s_t += tf;
      s_pt += p * tf;
      s_bce += x * (1.f - tf) + __logf(1.f + e);
    }
  }
  float r;
  r = block_reduce_256(s_bce, smr, tid);
  if (tid == 0) bceA[blockIdx.x] = r;
  r = block_reduce_256(s_p, smr, tid);
  if (tid == 0) spA[blockIdx.x] = r;
  r = block_reduce_256(s_t, smr, tid);
  if (tid == 0) stA[blockIdx.x] = r;
  r = block_reduce_256(s_pt, smr, tid);
  if (tid == 0) sptA[blockIdx.x] = r;
}

// CH==0: src map = sigmoid(logits), oth map = target.
// CH==1: src map = target,          oth map = sigmoid(logits).
// EDGE: row clamp needed only for bands 0 and 15 (y0-11 >= 0 and y0+42 <= 511
// otherwise). Interior bands drop the clamp -> LLVM strength-reduces the 88
// unrolled load addresses to incremental adds.
template <int CH, bool EDGE>
__device__ __forceinline__ float load_src(const float* __restrict__ Lg,
                                          const int* __restrict__ Tg, int gy,
                                          int colc) {
  if constexpr (EDGE) gy = min(max(gy, 0), H - 1);
  if constexpr (CH == 0) {
    float x = Lg[gy * W + colc];
    float e = __expf(-x);
    return __builtin_amdgcn_rcpf(1.f + e);
  } else {
    return (float)Tg[gy * W + colc];
  }
}

// ---- dilation steps via template recursion.
// R2 post-mortem: a runtime d-loop around `for (r=d; r<=51-d; ++r)` defeats
// nested full-unroll -> runtime-indexed a[] -> arrays demoted to scratch.
// With D a template parameter every index is compile-time, SROA promotes
// a[]/o[] to registers structurally, independent of unroll heuristics.
template <int D>
__device__ __forceinline__ void dilate_steps(float (&a)[52],
                                             const float (&o)[32],
                                             float& acc) {
  if constexpr (D <= 10) {
    float hp = hmax3(a[D - 1]);
    float hc = hmax3(a[D]);
#pragma unroll
    for (int r = D; r <= 51 - D; ++r) {  // trip count 52-2D: compile-time
      float hn = hmax3(a[r + 1]);
      float nv = fmaxf(fmaxf(hp, hc), hn);
      hp = hc;
      hc = hn;
      a[r] = nv;
    }
    constexpr float wd = 0.1f * (float)D;
#pragma unroll
    for (int k = 0; k < 32; ++k) acc += wd * fabsf(a[10 + k] - o[k]);
    dilate_steps<D + 1>(a, o, acc);
  }
}

// ---------------- fused: boundary-in-register + 10-step dilation ------------
// One wave per (strip, band, img, chain). Boundary maps are never
// materialized in global memory: the 3x3 dil-ero stencil is computed with the
// same DPP horizontal max/min + rolling vertical registers the dilation chain
// uses. BCE/dice work hoisted to bce_kernel (R4): CH0 and CH1 waves are now
// identical-cost (no chain imbalance in the tail).
template <int CH, bool EDGE>
__device__ __forceinline__ void fused_body(const float* __restrict__ Lg,
                                           const int* __restrict__ Tg,
                                           int lane, int strip, int band,
                                           int bz,
                                           float* __restrict__ chain_p) {
  int col = strip * CENT - 11 + lane;
  int colc = min(max(col, 0), W - 1);
  int y0 = band * 32;

  // ---- other-map boundary, central rows y0..y0+31 (rolling 3-row stencil)
  float o[32];
  {
    float v0 = load_src<1 - CH, EDGE>(Lg, Tg, y0 - 1, colc);
    float v1 = load_src<1 - CH, EDGE>(Lg, Tg, y0, colc);
    float hx0 = hmax3(v0), hn0 = hmin3(v0);
    float hx1 = hmax3(v1), hn1 = hmin3(v1);
#pragma unroll
    for (int k = 0; k < 32; ++k) {
      float v2 = load_src<1 - CH, EDGE>(Lg, Tg, y0 + 1 + k, colc);
      float hx2 = hmax3(v2), hn2 = hmin3(v2);
      o[k] = fmaxf(fmaxf(hx0, hx1), hx2) - fminf(fminf(hn0, hn1), hn2);
      hx0 = hx1;
      hx1 = hx2;
      hn0 = hn1;
      hn1 = hn2;
    }
  }

  // ---- src-map boundary incl. vertical halo: rows y0-10 .. y0+41
  float a[52];
  {
    float v0 = load_src<CH, EDGE>(Lg, Tg, y0 - 11, colc);
    float v1 = load_src<CH, EDGE>(Lg, Tg, y0 - 10, colc);
    float hx0 = hmax3(v0), hn0 = hmin3(v0);
    float hx1 = hmax3(v1), hn1 = hmin3(v1);
#pragma unroll
    for (int r = 0; r < 52; ++r) {
      float v2 = load_src<CH, EDGE>(Lg, Tg, y0 - 9 + r, colc);
      float hx2 = hmax3(v2), hn2 = hmin3(v2);
      a[r] = fmaxf(fmaxf(hx0, hx1), hx2) - fminf(fminf(hn0, hn1), hn2);
      hx0 = hx1;
      hx1 = hx2;
      hn0 = hn1;
      hn1 = hn2;
    }
  }

  // ---- 10-step register-resident dilation + weighted L1 accumulation
  float acc = 0.f;
  dilate_steps<1>(a, o, acc);

  bool valid = (lane >= 11 && lane <= 52 && col < W);
  acc = valid ? acc : 0.f;
  acc = wave_sum(acc);
  if (lane == 0) chain_p[(bz * NBAND + band) * NSTRIP + strip] = acc;
}

// 256-thread blocks, 4 independent waves each. __launch_bounds__(256, 4) =>
// 4 blocks/CU => 128-reg/thread budget (unified VGPR+AGPR file on gfx950)
// so a[52]+o[32]+rolling temps stay register-resident (R3: WRITE_SIZE
// collapsed to partials-only, no scratch).
__global__ void __launch_bounds__(256, 4) fused_kernel(
    const float* __restrict__ logits, const int* __restrict__ target,
    float* __restrict__ chain_p) {
  int tid = threadIdx.x;
  int lane = tid & 63;
  int wv = tid >> 6;
  int widx = blockIdx.x * 4 + wv;  // 0..6655, exact (NWORK/4 blocks)
  int strip = widx % NSTRIP;
  int rest = widx / NSTRIP;
  int band = rest & 15;
  int bz = rest >> 4;  // 0..31
  int img = bz & 15, chain = bz >> 4;
  const float* Lg = logits + (size_t)img * HWc;
  const int* Tg = target + (size_t)img * HWc;
  bool edge = (band == 0) | (band == 15);
  if (chain == 0) {
    if (edge)
      fused_body<0, true>(Lg, Tg, lane, strip, band, bz, chain_p);
    else
      fused_body<0, false>(Lg, Tg, lane, strip, band, bz, chain_p);
  } else {
    if (edge)
      fused_body<1, true>(Lg, Tg, lane, strip, band, bz, chain_p);
    else
      fused_body<1, false>(Lg, Tg, lane, strip, band, bz, chain_p);
  }
}

// ---------------- finalize ----------------
__global__ void finalize_kernel(const float* __restrict__ bceA,
                                const float* __restrict__ spA,
                                const float* __restrict__ stA,
                                const float* __restrict__ sptA,
                                const float* __restrict__ chain_p,
                                float* __restrict__ out) {
  __shared__ float smr[4];
  __shared__ float smImg[16][3];
  __shared__ double smd[16][2];
  int tid = threadIdx.x;

  float s = 0.f;
  for (int i = tid; i < NBCE; i += 256) s += bceA[i];  // 1024
  float bce_sum = block_reduce_256(s, smr, tid);

  s = 0.f;
  for (int i = tid; i < NWORK; i += 256) s += chain_p[i];  // 6656
  float hd_sum = block_reduce_256(s, smr, tid);

  {
    int img = tid >> 4, part = tid & 15;  // 16 threads per image
    float sp = 0.f, st = 0.f, spt = 0.f;
    for (int j = part; j < 64; j += 16) {  // 64 partials/image, 4 iters
      int idx = img * 64 + j;
      sp += spA[idx];
      st += stA[idx];
      spt += sptA[idx];
    }
#pragma unroll
    for (int off = 8; off > 0; off >>= 1) {
      sp += __shfl_down(sp, off, 16);
      st += __shfl_down(st, off, 16);
      spt += __shfl_down(spt, off, 16);
    }
    if (part == 0) {
      smImg[img][0] = sp;
      smImg[img][1] = st;
      smImg[img][2] = spt;
    }
  }
  __syncthreads();
  if (tid < 16) {
    double sp = smImg[tid][0], st = smImg[tid][1], spt = smImg[tid][2];
    double dice = (2.0 * spt + 1e-6) / (sp + st + 1e-6 + 1e-7);
    double tv = (spt + 1e-6) /
                (spt + 0.7 * (sp - spt) + 0.3 * (st - spt) + 1e-6 + 1e-7);
    smd[tid][0] = 1.0 - dice;
    smd[tid][1] = pow(1.0 - tv, 0.75);
  }
  __syncthreads();
  if (tid == 0) {
    double dice_l = 0.0, ft_l = 0.0;
    for (int i = 0; i < 16; ++i) {
      dice_l += smd[i][0];
      ft_l += smd[i][1];
    }
    dice_l /= 16.0;
    ft_l /= 16.0;
    const double Nd = (double)Nc;
    double bce = (double)bce_sum / Nd;
    double hd = ((double)hd_sum / Nd) / (5.5 + 1e-8);
    out[0] = (float)(bce + dice_l + ft_l + 0.1 * hd);
  }
}

}  // namespace

extern "C" void kernel_launch(void* const* d_in, const int* in_sizes, int n_in,
                              void* d_out, int out_size, void* d_ws,
                              size_t ws_size, hipStream_t stream) {
  const float* logits = (const float*)d_in[0];
  const int* target = (const int*)d_in[1];
  float* out = (float*)d_out;

  // Workspace: only small partial arrays (boundary maps never hit global).
  // All slots below are fully written each launch.
  float* part = (float*)d_ws;
  float* bceA = part;                  // 1024
  float* spA = part + NBCE;            // 1024
  float* stA = part + 2 * NBCE;        // 1024
  float* sptA = part + 3 * NBCE;       // 1024
  float* chain_p = part + 4 * NBCE;    // 6656 = 32*16*13

  bce_kernel<<<dim3(NBCE), dim3(256), 0, stream>>>(logits, target, bceA, spA,
                                                   stA, sptA);
  fused_kernel<<<dim3(NWORK / 4), dim3(256), 0, stream>>>(logits, target,
                                                          chain_p);
  finalize_kernel<<<1, 256, 0, stream>>>(bceA, spA, stA, sptA, chain_p, out);
}